// Round 9
// baseline (220.981 us; speedup 1.0000x reference)
//
#include <hip/hip_runtime.h>
#include <math.h>

typedef float f4 __attribute__((ext_vector_type(4)));
typedef float f2 __attribute__((ext_vector_type(2)));

#define L_LEN 2048
#define C_DIM 96
#define N_DIM 16
#define R_DIM 6
#define G_DIM 12
#define B_DIM 4
#define NCHUNK 64
#define CLEN 32
#define WINL 128
#define BGC (B_DIM * G_DIM * C_DIM) // 4608

// workspace layout (floats)
#define SZ_DTS (B_DIM * G_DIM * L_LEN * R_DIM)   // 589824
#define SZ_BC (B_DIM * G_DIM * N_DIM * L_LEN)    // 1572864
#define SZ_U6 (B_DIM * 6 * C_DIM * L_LEN)        // 4718592
#define SZ_Y (B_DIM * G_DIM * C_DIM * L_LEN)     // 9437184
#define SZ_H (BGC * NCHUNK * N_DIM)              // 4718592
#define SZ_X (B_DIM * 2 * C_DIM * 1024)          // 786432
#define SZ_WPAD (G_DIM * 40 * C_DIM)             // 46080

// ---------------- K0: transpose x (H<->W) for odd-k coalescing ----------------
__global__ __launch_bounds__(256) void k0_xT(
    const float* __restrict__ x, float* __restrict__ xT)
{
    __shared__ float t[32][33];
    int img = blockIdx.x; // (b,s,c) image, 768 total
    const float* src = x + (size_t)img * 1024;
    float* dst = xT + (size_t)img * 1024;
    int tx = threadIdx.x & 31, ty = threadIdx.x >> 5;
#pragma unroll
    for (int r = 0; r < 32; r += 8) t[ty + r][tx] = src[(ty + r) * 32 + tx];
    __syncthreads();
#pragma unroll
    for (int r = 0; r < 32; r += 8) dst[(ty + r) * 32 + tx] = t[tx][ty + r];
}

// ---------------- K0b: zero-pad x_proj_weight rows 38->40 ----------------
__global__ __launch_bounds__(256) void k0b_padw(
    const float* __restrict__ xpw, float* __restrict__ wpad)
{
    int i = blockIdx.x * 256 + (int)threadIdx.x; // < 46080
    if (i >= G_DIM * 40 * C_DIM) return;
    int g = i / (40 * C_DIM);
    int rem = i - g * 40 * C_DIM;
    int p = rem / C_DIM, c = rem - (rem / C_DIM) * C_DIM;
    wpad[i] = (p < 38) ? xpw[((size_t)g * 38 + p) * C_DIM + c] : 0.f;
}

// ---------------- K1: paired cross-scan gather + projections ----------------
__global__ __launch_bounds__(256) void k1_proj(
    const float* __restrict__ x, const float* __restrict__ xT,
    const float* __restrict__ wpad,
    float* __restrict__ dtsT, float* __restrict__ Bsw,
    float* __restrict__ Csw, float* __restrict__ u6T)
{
    __shared__ float Vsh[C_DIM * 68];
    __shared__ float Psh[40][68];

    int blk = blockIdx.x;      // bks*32 + ltile
    int ltile = blk & 31;
    int bks = blk >> 5;        // 0..23
    int s = bks % 3;
    int k = (bks / 3) & 1;
    int b = bks / 6;
    int g = k * 3 + s;         // 0..5
    int gh = g + 6;
    int l0 = ltile * 64;
    int l0h = (31 - ltile) * 64;
    int bg = b * G_DIM + g;
    int bgh = b * G_DIM + gh;
    int tid = (int)threadIdx.x;

    const float* xb = (k ? xT : x) + (size_t)b * 2 * C_DIM * 1024;

    // ---- stage V[c][ll] (f2 loads, f4 LDS writes) ----
#pragma unroll
    for (int j = 0; j < 6; ++j) {
        int e = tid + j * 256;       // < 1536
        int c = e >> 4;
        int llq = (e & 15) * 4;
        int pp = (l0 + llq) >> 1;
        f2 x0 = *(const f2*)(xb + (size_t)c * 1024 + pp);
        f2 x1 = *(const f2*)(xb + (size_t)(C_DIM + c) * 1024 + pp);
        f4 v;
        if (s == 2)      { v[0] = x0.x; v[1] = x1.x; v[2] = x0.y; v[3] = x1.y; }
        else if (s == 1) { v[0] = x1.x - x0.x; v[1] = x1.x; v[2] = x1.y - x0.y; v[3] = x1.y; }
        else             { v[0] = x0.x - x1.x; v[1] = x0.x; v[2] = x0.y - x1.y; v[3] = x0.y; }
        *(f4*)(Vsh + c * 68 + llq) = v;
    }
    __syncthreads();

    // ---- u6T[b6g][l][c] (coalesced f4, g<6 always here) ----
    {
        size_t ub = ((size_t)(b * 6 + g) * L_LEN + l0) * C_DIM;
#pragma unroll
        for (int j = 0; j < 6; ++j) {
            int e = tid + j * 256;
            int lidx = e / 24;
            int c4 = (e - lidx * 24) * 4;
            f4 v = { Vsh[(c4 + 0) * 68 + lidx], Vsh[(c4 + 1) * 68 + lidx],
                     Vsh[(c4 + 2) * 68 + lidx], Vsh[(c4 + 3) * 68 + lidx] };
            *(f4*)(u6T + ub + (size_t)lidx * C_DIM + c4) = v;
        }
    }

    // ---- register GEMM for g and gh (weights via scalar f4 loads) ----
    int ll = tid & 63;
    int P0 = __builtin_amdgcn_readfirstlane((tid >> 6) * 10);
    const float* wp = wpad + (size_t)g * 3840 + (size_t)P0 * C_DIM;
    const float* wph = wpad + (size_t)gh * 3840 + (size_t)P0 * C_DIM;

    float acc[10], acch[10];
#pragma unroll
    for (int p = 0; p < 10; ++p) { acc[p] = 0.f; acch[p] = 0.f; }

    for (int cb = 0; cb < C_DIM; cb += 8) {
        float vc[8], vch[8];
#pragma unroll
        for (int i = 0; i < 8; ++i) {
            vc[i] = Vsh[(cb + i) * 68 + ll];
            vch[i] = Vsh[(cb + i) * 68 + 63 - ll];
        }
#pragma unroll
        for (int p = 0; p < 10; ++p) {
#pragma unroll
            for (int q = 0; q < 2; ++q) {
                f4 w = *(const f4*)(wp + p * C_DIM + cb + q * 4);
                f4 wh = *(const f4*)(wph + p * C_DIM + cb + q * 4);
#pragma unroll
                for (int i = 0; i < 4; ++i) {
                    acc[p] = fmaf(w[i], vc[q * 4 + i], acc[p]);
                    acch[p] = fmaf(wh[i], vch[q * 4 + i], acch[p]);
                }
            }
        }
    }

    // ---- transpose via Psh, coalesced stores (g then gh) ----
#pragma unroll
    for (int gg = 0; gg < 2; ++gg) {
        __syncthreads();
#pragma unroll
        for (int p = 0; p < 10; ++p) Psh[P0 + p][ll] = gg ? acch[p] : acc[p];
        __syncthreads();
        int lb = gg ? l0h : l0;
        int bgx = gg ? bgh : bg;
        int q = tid & 3, lx = tid >> 2;
        f4 bv = { Psh[6 + q * 4 + 0][lx], Psh[6 + q * 4 + 1][lx],
                  Psh[6 + q * 4 + 2][lx], Psh[6 + q * 4 + 3][lx] };
        *(f4*)(Bsw + ((size_t)bgx * L_LEN + lb + lx) * N_DIM + q * 4) = bv;
        f4 cv = { Psh[22 + q * 4 + 0][lx], Psh[22 + q * 4 + 1][lx],
                  Psh[22 + q * 4 + 2][lx], Psh[22 + q * 4 + 3][lx] };
        *(f4*)(Csw + ((size_t)bgx * L_LEN + lb + lx) * N_DIM + q * 4) = cv;
        for (int e = tid; e < 64 * R_DIM; e += 256) {
            int lx2 = e / 6, r = e - (e / 6) * 6;
            dtsT[((size_t)bgx * L_LEN + lb + lx2) * R_DIM + r] = Psh[r][lx2];
        }
    }
}

// ---------------- K2: chunk-parallel scan, 2 streams per thread ----------------
__device__ __forceinline__ float softplus_f(float x)
{
    float sp = __logf(1.f + __expf(x));
    return (x > 60.f) ? x : sp;
}

// Pass A: per chunk with h0=0, compute h_end[16] and prodE[16]=exp2(a2*S).
// block = 192 thr = 96c x 2 slots; each thread scans 2 chunks of a 128-l window.
__global__ __launch_bounds__(192) void k2_scanA(
    const float* __restrict__ dtsT, const float* __restrict__ Bsw,
    const float* __restrict__ u6T, const float* __restrict__ A_logs,
    const float* __restrict__ dtw, const float* __restrict__ dtb,
    float* __restrict__ hend, float* __restrict__ prodE)
{
    __shared__ f4 Bsh[512];     // 128 l x 16 n
    __shared__ float Dsh[768];  // 128 l x 6
    int blk = blockIdx.x;
    int win = blk & 15;
    int bg = blk >> 4;
    int g = bg % G_DIM;
    int b = bg / G_DIM;
    int tid = (int)threadIdx.x;

    const f4* Bg = (const f4*)(Bsw + ((size_t)bg * L_LEN + win * WINL) * N_DIM);
    for (int i = tid; i < 512; i += 192) Bsh[i] = Bg[i];
    const float* Dg = dtsT + ((size_t)bg * L_LEN + win * WINL) * R_DIM;
    for (int i = tid; i < 768; i += 192) Dsh[i] = Dg[i];
    __syncthreads();

    int slot = tid / 96;
    int c = tid % 96;
    int ch0 = win * 4 + slot;
    int ch1 = ch0 + 2;
    int bgc = bg * C_DIM + c;
    const bool rev = (g >= 6);
    int gu = rev ? (g - 6) : g;

    float a2[N_DIM];
    {
        const f4* Ap = (const f4*)(A_logs + ((size_t)g * C_DIM + c) * N_DIM);
        f4 Av[4] = { Ap[0], Ap[1], Ap[2], Ap[3] };
#pragma unroll
        for (int n = 0; n < N_DIM; ++n)
            a2[n] = -__expf(Av[n >> 2][n & 3]) * 1.44269504f;
    }
    float wdr[R_DIM];
    {
        const float* wdp = dtw + ((size_t)g * C_DIM + c) * R_DIM;
#pragma unroll
        for (int r = 0; r < R_DIM; ++r) wdr[r] = wdp[r];
    }
    float bias = dtb[g * C_DIM + c];

    const int L0 = ch0 * CLEN;
    const int L1 = ch1 * CLEN;
    const int lo0 = slot * CLEN;
    const int lo1 = lo0 + 2 * CLEN;

    const float* ubase = u6T + (size_t)(b * 6 + gu) * L_LEN * C_DIM + c;
    const float *up0, *up1;
    int us;
    if (rev) { up0 = ubase + (size_t)(2047 - L0) * C_DIM; up1 = ubase + (size_t)(2047 - L1) * C_DIM; us = -C_DIM; }
    else     { up0 = ubase + (size_t)L0 * C_DIM; up1 = ubase + (size_t)L1 * C_DIM; us = C_DIM; }

    float h0[N_DIM], h1[N_DIM];
#pragma unroll
    for (int n = 0; n < N_DIM; ++n) { h0[n] = 0.f; h1[n] = 0.f; }
    float S0 = 0.f, S1 = 0.f;

    float u0[4], u1[4];
#pragma unroll
    for (int j = 0; j < 4; ++j) { u0[j] = up0[j * us]; u1[j] = up1[j * us]; }

    for (int jj = 0; jj < CLEN; jj += 4) {
        int nx = (jj + 4 < CLEN) ? jj + 4 : jj;
        float un0[4], un1[4];
#pragma unroll
        for (int j = 0; j < 4; ++j) { un0[j] = up0[(nx + j) * us]; un1[j] = up1[(nx + j) * us]; }
#pragma unroll
        for (int j = 0; j < 4; ++j) {
            int li0 = lo0 + jj + j;
            int li1 = lo1 + jj + j;
            float dt0 = bias, dt1 = bias;
#pragma unroll
            for (int r = 0; r < R_DIM; ++r) {
                dt0 = fmaf(Dsh[li0 * R_DIM + r], wdr[r], dt0);
                dt1 = fmaf(Dsh[li1 * R_DIM + r], wdr[r], dt1);
            }
            float d0 = softplus_f(dt0);
            float d1 = softplus_f(dt1);
            S0 += d0; S1 += d1;
            float du0 = d0 * u0[j];
            float du1 = d1 * u1[j];
            const f4* Bl0 = Bsh + (size_t)li0 * 4;
            const f4* Bl1 = Bsh + (size_t)li1 * 4;
            f4 Bv0[4] = { Bl0[0], Bl0[1], Bl0[2], Bl0[3] };
            f4 Bv1[4] = { Bl1[0], Bl1[1], Bl1[2], Bl1[3] };
#pragma unroll
            for (int n = 0; n < N_DIM; ++n) {
                float e0 = exp2f(d0 * a2[n]);
                float e1 = exp2f(d1 * a2[n]);
                h0[n] = fmaf(h0[n], e0, du0 * Bv0[n >> 2][n & 3]);
                h1[n] = fmaf(h1[n], e1, du1 * Bv1[n >> 2][n & 3]);
            }
        }
#pragma unroll
        for (int j = 0; j < 4; ++j) { u0[j] = un0[j]; u1[j] = un1[j]; }
    }
    float* hp0 = hend + ((size_t)bgc * NCHUNK + ch0) * N_DIM;
    float* pp0 = prodE + ((size_t)bgc * NCHUNK + ch0) * N_DIM;
    float* hp1 = hend + ((size_t)bgc * NCHUNK + ch1) * N_DIM;
    float* pp1 = prodE + ((size_t)bgc * NCHUNK + ch1) * N_DIM;
#pragma unroll
    for (int q = 0; q < 4; ++q) {
        f4 hv0 = { h0[q * 4], h0[q * 4 + 1], h0[q * 4 + 2], h0[q * 4 + 3] };
        f4 pv0 = { exp2f(a2[q * 4] * S0), exp2f(a2[q * 4 + 1] * S0),
                   exp2f(a2[q * 4 + 2] * S0), exp2f(a2[q * 4 + 3] * S0) };
        *(f4*)(hp0 + q * 4) = hv0;
        *(f4*)(pp0 + q * 4) = pv0;
        f4 hv1 = { h1[q * 4], h1[q * 4 + 1], h1[q * 4 + 2], h1[q * 4 + 3] };
        f4 pv1 = { exp2f(a2[q * 4] * S1), exp2f(a2[q * 4 + 1] * S1),
                   exp2f(a2[q * 4 + 2] * S1), exp2f(a2[q * 4 + 3] * S1) };
        *(f4*)(hp1 + q * 4) = hv1;
        *(f4*)(pp1 + q * 4) = pv1;
    }
}

// Pass B: compose chunk propagators. Overwrites prodE with hstart (in place).
__global__ __launch_bounds__(256) void k2_fix(
    const float* __restrict__ hend, float* prodE_hstart)
{
    int t = blockIdx.x * 256 + (int)threadIdx.x; // 73728
    int n = t & 15;
    int bgc = t >> 4;
    float h = 0.f;
    for (int ch = 0; ch < NCHUNK; ++ch) {
        size_t idx = ((size_t)bgc * NCHUNK + ch) * N_DIM + n;
        float Pv = prodE_hstart[idx];
        float he = hend[idx];
        prodE_hstart[idx] = h;
        h = fmaf(h, Pv, he);
    }
}

// Pass C: exact recurrence from hstart, writes yT [bg][l][c] (+Ds*u folded).
__global__ __launch_bounds__(192) void k2_scanC(
    const float* __restrict__ dtsT, const float* __restrict__ Bsw,
    const float* __restrict__ Csw, const float* __restrict__ u6T,
    const float* __restrict__ A_logs, const float* __restrict__ Ds,
    const float* __restrict__ dtw, const float* __restrict__ dtb,
    const float* __restrict__ hstart, float* __restrict__ yssT)
{
    __shared__ f4 Bsh[512];
    __shared__ f4 Csh[512];
    __shared__ float Dsh[768];
    int blk = blockIdx.x;
    int win = blk & 15;
    int bg = blk >> 4;
    int g = bg % G_DIM;
    int b = bg / G_DIM;
    int tid = (int)threadIdx.x;

    const f4* Bg = (const f4*)(Bsw + ((size_t)bg * L_LEN + win * WINL) * N_DIM);
    const f4* Cg = (const f4*)(Csw + ((size_t)bg * L_LEN + win * WINL) * N_DIM);
    for (int i = tid; i < 512; i += 192) { Bsh[i] = Bg[i]; Csh[i] = Cg[i]; }
    const float* Dg = dtsT + ((size_t)bg * L_LEN + win * WINL) * R_DIM;
    for (int i = tid; i < 768; i += 192) Dsh[i] = Dg[i];
    __syncthreads();

    int slot = tid / 96;
    int c = tid % 96;
    int ch0 = win * 4 + slot;
    int ch1 = ch0 + 2;
    int bgc = bg * C_DIM + c;
    const bool rev = (g >= 6);
    int gu = rev ? (g - 6) : g;

    float a2[N_DIM];
    {
        const f4* Ap = (const f4*)(A_logs + ((size_t)g * C_DIM + c) * N_DIM);
        f4 Av[4] = { Ap[0], Ap[1], Ap[2], Ap[3] };
#pragma unroll
        for (int n = 0; n < N_DIM; ++n)
            a2[n] = -__expf(Av[n >> 2][n & 3]) * 1.44269504f;
    }
    float wdr[R_DIM];
    {
        const float* wdp = dtw + ((size_t)g * C_DIM + c) * R_DIM;
#pragma unroll
        for (int r = 0; r < R_DIM; ++r) wdr[r] = wdp[r];
    }
    float bias = dtb[g * C_DIM + c];
    float dsc = Ds[g * C_DIM + c];

    const int L0 = ch0 * CLEN;
    const int L1 = ch1 * CLEN;
    const int lo0 = slot * CLEN;
    const int lo1 = lo0 + 2 * CLEN;

    const float* ubase = u6T + (size_t)(b * 6 + gu) * L_LEN * C_DIM + c;
    const float *up0, *up1;
    int us;
    if (rev) { up0 = ubase + (size_t)(2047 - L0) * C_DIM; up1 = ubase + (size_t)(2047 - L1) * C_DIM; us = -C_DIM; }
    else     { up0 = ubase + (size_t)L0 * C_DIM; up1 = ubase + (size_t)L1 * C_DIM; us = C_DIM; }
    float* yp0 = yssT + ((size_t)bg * L_LEN + L0) * C_DIM + c;
    float* yp1 = yssT + ((size_t)bg * L_LEN + L1) * C_DIM + c;

    float h0[N_DIM], h1[N_DIM];
    {
        const f4* Hp0 = (const f4*)(hstart + ((size_t)bgc * NCHUNK + ch0) * N_DIM);
        const f4* Hp1 = (const f4*)(hstart + ((size_t)bgc * NCHUNK + ch1) * N_DIM);
        f4 Hv0[4] = { Hp0[0], Hp0[1], Hp0[2], Hp0[3] };
        f4 Hv1[4] = { Hp1[0], Hp1[1], Hp1[2], Hp1[3] };
#pragma unroll
        for (int n = 0; n < N_DIM; ++n) { h0[n] = Hv0[n >> 2][n & 3]; h1[n] = Hv1[n >> 2][n & 3]; }
    }

    float u0[4], u1[4];
#pragma unroll
    for (int j = 0; j < 4; ++j) { u0[j] = up0[j * us]; u1[j] = up1[j * us]; }

    for (int jj = 0; jj < CLEN; jj += 4) {
        int nx = (jj + 4 < CLEN) ? jj + 4 : jj;
        float un0[4], un1[4];
#pragma unroll
        for (int j = 0; j < 4; ++j) { un0[j] = up0[(nx + j) * us]; un1[j] = up1[(nx + j) * us]; }
#pragma unroll
        for (int j = 0; j < 4; ++j) {
            int li0 = lo0 + jj + j;
            int li1 = lo1 + jj + j;
            float dt0 = bias, dt1 = bias;
#pragma unroll
            for (int r = 0; r < R_DIM; ++r) {
                dt0 = fmaf(Dsh[li0 * R_DIM + r], wdr[r], dt0);
                dt1 = fmaf(Dsh[li1 * R_DIM + r], wdr[r], dt1);
            }
            float d0 = softplus_f(dt0);
            float d1 = softplus_f(dt1);
            float du0 = d0 * u0[j];
            float du1 = d1 * u1[j];
            const f4* Bl0 = Bsh + (size_t)li0 * 4;
            const f4* Bl1 = Bsh + (size_t)li1 * 4;
            const f4* Cl0 = Csh + (size_t)li0 * 4;
            const f4* Cl1 = Csh + (size_t)li1 * 4;
            f4 Bv0[4] = { Bl0[0], Bl0[1], Bl0[2], Bl0[3] };
            f4 Bv1[4] = { Bl1[0], Bl1[1], Bl1[2], Bl1[3] };
            f4 Cv0[4] = { Cl0[0], Cl0[1], Cl0[2], Cl0[3] };
            f4 Cv1[4] = { Cl1[0], Cl1[1], Cl1[2], Cl1[3] };
            float y0 = dsc * u0[j];
            float y1 = dsc * u1[j];
#pragma unroll
            for (int n = 0; n < N_DIM; ++n) {
                float e0 = exp2f(d0 * a2[n]);
                float e1 = exp2f(d1 * a2[n]);
                h0[n] = fmaf(h0[n], e0, du0 * Bv0[n >> 2][n & 3]);
                h1[n] = fmaf(h1[n], e1, du1 * Bv1[n >> 2][n & 3]);
                y0 = fmaf(h0[n], Cv0[n >> 2][n & 3], y0);
                y1 = fmaf(h1[n], Cv1[n >> 2][n & 3], y1);
            }
            yp0[(jj + j) * C_DIM] = y0;
            yp1[(jj + j) * C_DIM] = y1;
        }
#pragma unroll
        for (int j = 0; j < 4; ++j) { u0[j] = un0[j]; u1[j] = un1[j]; }
    }
}

// ---------------- K3: fold (un-scan) + LayerNorm, fused ([l][c] input) ----------------
__global__ __launch_bounds__(256) void k3_out(
    const float* __restrict__ yssT, const float* __restrict__ nw,
    const float* __restrict__ nb, float* __restrict__ out)
{
    __shared__ float tA[32][97];
    __shared__ float tB[32][97];
    __shared__ float ps[4][8][32];
    __shared__ float stat[4][32];

    int blk = blockIdx.x;
    int h = blk & 31;
    int bs = blk >> 5;
    int so = bs & 1;
    int b = bs >> 1;
    int tid = (int)threadIdx.x;

    auto Y = [&](int g) { return yssT + (size_t)(b * 12 + g) * L_LEN * C_DIM; };
    const float* Y0 = Y(so);
    const float* Y0r = Y(6 + so);
    const float* Y1 = Y(3 + so);
    const float* Y1r = Y(9 + so);

#pragma unroll 2
    for (int it = 0; it < 24; ++it) {
        int idx = tid + it * 256;
        int c = idx % 96, rest = idx / 96;
        int w = rest >> 1, par = rest & 1;
        int a0 = h * 64 + rest;
        int a1 = w * 64 + 2 * h + par;
        float v = Y0[(size_t)a0 * C_DIM + c] + Y0r[(size_t)(2047 - a0) * C_DIM + c]
                + Y1[(size_t)a1 * C_DIM + c] + Y1r[(size_t)(2047 - a1) * C_DIM + c];
        if (par) tA[w][c] = v; else tB[w][c] = v;
    }
    __syncthreads();

    int w = tid & 31, cg = tid >> 5;
    float sA = 0, qA = 0, sB = 0, qB = 0;
#pragma unroll
    for (int j = 0; j < 12; ++j) {
        float yv = tA[w][cg * 12 + j], dv = tB[w][cg * 12 + j];
        sA += yv; qA += yv * yv; sB += dv; qB += dv * dv;
    }
    ps[0][cg][w] = sA; ps[1][cg][w] = qA; ps[2][cg][w] = sB; ps[3][cg][w] = qB;
    __syncthreads();
    if (tid < 32) {
        int ww = tid;
        float t0 = 0, t1 = 0, t2 = 0, t3 = 0;
#pragma unroll
        for (int q = 0; q < 8; ++q) {
            t0 += ps[0][q][ww]; t1 += ps[1][q][ww];
            t2 += ps[2][q][ww]; t3 += ps[3][q][ww];
        }
        float muA = t0 * (1.f / 96.f), eqA = t1 * (1.f / 96.f);
        float muB = t2 * (1.f / 96.f), eqB = t3 * (1.f / 96.f);
        stat[0][ww] = muA; stat[1][ww] = rsqrtf(eqA - muA * muA + 1e-5f);
        stat[2][ww] = muB; stat[3][ww] = rsqrtf(eqB - muB * muB + 1e-5f);
    }
    __syncthreads();
    size_t obase = (size_t)blk * 3072;
    for (int e = tid; e < 3072; e += 256) {
        int ww = e / 96, c = e % 96;
        float wc = nw[c], bc = nb[c];
        out[obase + e] = (tA[ww][c] - stat[0][ww]) * stat[1][ww] * wc + bc;
        out[2 * 786432 + obase + e] = (tB[ww][c] - stat[2][ww]) * stat[3][ww] * wc + bc;
    }
    __syncthreads();

    const float* Y2 = Y(2);
    const float* Y2r = Y(8);
    const float* Y3 = Y(5);
    const float* Y3r = Y(11);
#pragma unroll 2
    for (int it = 0; it < 12; ++it) {
        int idx = tid + it * 256;
        int c = idx % 96, w2 = idx / 96;
        int a0 = h * 64 + 2 * w2 + so;
        int a1 = w2 * 64 + 2 * h + so;
        float v = Y2[(size_t)a0 * C_DIM + c] + Y2r[(size_t)(2047 - a0) * C_DIM + c]
                + Y3[(size_t)a1 * C_DIM + c] + Y3r[(size_t)(2047 - a1) * C_DIM + c];
        tA[w2][c] = v;
    }
    __syncthreads();
    float sC = 0, qC = 0;
#pragma unroll
    for (int j = 0; j < 12; ++j) {
        float v = tA[w][cg * 12 + j];
        sC += v; qC += v * v;
    }
    ps[0][cg][w] = sC; ps[1][cg][w] = qC;
    __syncthreads();
    if (tid < 32) {
        int ww = tid;
        float t0 = 0, t1 = 0;
#pragma unroll
        for (int q = 0; q < 8; ++q) { t0 += ps[0][q][ww]; t1 += ps[1][q][ww]; }
        float mu = t0 * (1.f / 96.f), eq = t1 * (1.f / 96.f);
        stat[0][ww] = mu; stat[1][ww] = rsqrtf(eq - mu * mu + 1e-5f);
    }
    __syncthreads();
    for (int e = tid; e < 3072; e += 256) {
        int ww = e / 96, c = e % 96;
        out[786432 + obase + e] = (tA[ww][c] - stat[0][ww]) * stat[1][ww] * nw[c] + nb[c];
    }
}

extern "C" void kernel_launch(void* const* d_in, const int* in_sizes, int n_in,
                              void* d_out, int out_size, void* d_ws, size_t ws_size,
                              hipStream_t stream)
{
    const float* x = (const float*)d_in[0];
    const float* xpw = (const float*)d_in[1];
    const float* dtw = (const float*)d_in[2];
    const float* dtb = (const float*)d_in[3];
    const float* A_logs = (const float*)d_in[4];
    const float* Ds = (const float*)d_in[5];
    const float* nw = (const float*)d_in[6];
    const float* nb = (const float*)d_in[7];
    float* out = (float*)d_out;

    float* ws = (float*)d_ws;
    float* dtsT = ws;                  // SZ_DTS
    float* Bsw = dtsT + SZ_DTS;        // SZ_BC
    float* Csw = Bsw + SZ_BC;          // SZ_BC
    float* u6T = Csw + SZ_BC;          // SZ_U6
    float* yssT = u6T + SZ_U6;         // SZ_Y
    float* hend = yssT + SZ_Y;         // SZ_H
    float* prodE = hend + SZ_H;        // SZ_H (then reused as hstart)
    float* xT = prodE + SZ_H;          // SZ_X
    float* wpad = xT + SZ_X;           // SZ_WPAD

    k0_xT<<<dim3(768), dim3(256), 0, stream>>>(x, xT);
    k0b_padw<<<dim3(180), dim3(256), 0, stream>>>(xpw, wpad);
    k1_proj<<<dim3(24 * 32), dim3(256), 0, stream>>>(x, xT, wpad, dtsT, Bsw, Csw, u6T);
    k2_scanA<<<dim3(48 * 16), dim3(192), 0, stream>>>(dtsT, Bsw, u6T, A_logs, dtw, dtb, hend, prodE);
    k2_fix<<<dim3(288), dim3(256), 0, stream>>>(hend, prodE);
    k2_scanC<<<dim3(48 * 16), dim3(192), 0, stream>>>(dtsT, Bsw, Csw, u6T, A_logs, Ds, dtw, dtb, prodE, yssT);
    k3_out<<<dim3(256), dim3(256), 0, stream>>>(yssT, nw, nb, out);
}

// Round 10
// 154.298 us; speedup vs baseline: 1.4322x; 1.4322x over previous
//
#include <hip/hip_runtime.h>
#include <math.h>

typedef float f4 __attribute__((ext_vector_type(4)));
typedef float f2 __attribute__((ext_vector_type(2)));

#define L_LEN 2048
#define C_DIM 96
#define N_DIM 16
#define R_DIM 6
#define G_DIM 12
#define B_DIM 4
#define NCHUNK 64
#define CLEN 32
#define BGC (B_DIM * G_DIM * C_DIM) // 4608

// workspace layout (floats)
#define SZ_DTS (B_DIM * G_DIM * L_LEN * R_DIM)   // 589824
#define SZ_BC (B_DIM * G_DIM * N_DIM * L_LEN)    // 1572864
#define SZ_U6 (B_DIM * 6 * C_DIM * L_LEN)        // 4718592
#define SZ_Y (B_DIM * G_DIM * C_DIM * L_LEN)     // 9437184
#define SZ_H (BGC * NCHUNK * N_DIM)              // 4718592
#define SZ_X (B_DIM * 2 * C_DIM * 1024)          // 786432
#define SZ_WPAD (G_DIM * 40 * C_DIM)             // 46080

__device__ __forceinline__ float fexp2(float x) { return __builtin_amdgcn_exp2f(x); }

// ---------------- K0: transpose x (H<->W) for odd-k coalescing ----------------
__global__ __launch_bounds__(256) void k0_xT(
    const float* __restrict__ x, float* __restrict__ xT)
{
    __shared__ float t[32][33];
    int img = blockIdx.x; // (b,s,c) image, 768 total
    const float* src = x + (size_t)img * 1024;
    float* dst = xT + (size_t)img * 1024;
    int tx = threadIdx.x & 31, ty = threadIdx.x >> 5;
#pragma unroll
    for (int r = 0; r < 32; r += 8) t[ty + r][tx] = src[(ty + r) * 32 + tx];
    __syncthreads();
#pragma unroll
    for (int r = 0; r < 32; r += 8) dst[(ty + r) * 32 + tx] = t[tx][ty + r];
}

// ---------------- K0b: zero-pad x_proj_weight rows 38->40 ----------------
__global__ __launch_bounds__(256) void k0b_padw(
    const float* __restrict__ xpw, float* __restrict__ wpad)
{
    int i = blockIdx.x * 256 + (int)threadIdx.x; // < 46080
    if (i >= G_DIM * 40 * C_DIM) return;
    int g = i / (40 * C_DIM);
    int rem = i - g * 40 * C_DIM;
    int p = rem / C_DIM, c = rem - (rem / C_DIM) * C_DIM;
    wpad[i] = (p < 38) ? xpw[((size_t)g * 38 + p) * C_DIM + c] : 0.f;
}

// ---------------- K1: paired cross-scan gather + projections ----------------
__global__ __launch_bounds__(256) void k1_proj(
    const float* __restrict__ x, const float* __restrict__ xT,
    const float* __restrict__ wpad,
    float* __restrict__ dtsT, float* __restrict__ Bsw,
    float* __restrict__ Csw, float* __restrict__ u6T)
{
    __shared__ float Vsh[C_DIM * 68];
    __shared__ float Psh[40][68];

    int blk = blockIdx.x;      // bks*32 + ltile
    int ltile = blk & 31;
    int bks = blk >> 5;        // 0..23
    int s = bks % 3;
    int k = (bks / 3) & 1;
    int b = bks / 6;
    int g = k * 3 + s;         // 0..5
    int gh = g + 6;
    int l0 = ltile * 64;
    int l0h = (31 - ltile) * 64;
    int bg = b * G_DIM + g;
    int bgh = b * G_DIM + gh;
    int tid = (int)threadIdx.x;

    const float* xb = (k ? xT : x) + (size_t)b * 2 * C_DIM * 1024;

    // ---- stage V[c][ll] (f2 loads, f4 LDS writes) ----
#pragma unroll
    for (int j = 0; j < 6; ++j) {
        int e = tid + j * 256;       // < 1536
        int c = e >> 4;
        int llq = (e & 15) * 4;
        int pp = (l0 + llq) >> 1;
        f2 x0 = *(const f2*)(xb + (size_t)c * 1024 + pp);
        f2 x1 = *(const f2*)(xb + (size_t)(C_DIM + c) * 1024 + pp);
        f4 v;
        if (s == 2)      { v[0] = x0.x; v[1] = x1.x; v[2] = x0.y; v[3] = x1.y; }
        else if (s == 1) { v[0] = x1.x - x0.x; v[1] = x1.x; v[2] = x1.y - x0.y; v[3] = x1.y; }
        else             { v[0] = x0.x - x1.x; v[1] = x0.x; v[2] = x0.y - x1.y; v[3] = x0.y; }
        *(f4*)(Vsh + c * 68 + llq) = v;
    }
    __syncthreads();

    // ---- u6T[b6g][l][c] (coalesced f4, g<6 always here) ----
    {
        size_t ub = ((size_t)(b * 6 + g) * L_LEN + l0) * C_DIM;
#pragma unroll
        for (int j = 0; j < 6; ++j) {
            int e = tid + j * 256;
            int lidx = e / 24;
            int c4 = (e - lidx * 24) * 4;
            f4 v = { Vsh[(c4 + 0) * 68 + lidx], Vsh[(c4 + 1) * 68 + lidx],
                     Vsh[(c4 + 2) * 68 + lidx], Vsh[(c4 + 3) * 68 + lidx] };
            *(f4*)(u6T + ub + (size_t)lidx * C_DIM + c4) = v;
        }
    }

    // ---- register GEMM for g and gh (weights via scalar f4 loads) ----
    int ll = tid & 63;
    int P0 = __builtin_amdgcn_readfirstlane((tid >> 6) * 10);
    const float* wp = wpad + (size_t)g * 3840 + (size_t)P0 * C_DIM;
    const float* wph = wpad + (size_t)gh * 3840 + (size_t)P0 * C_DIM;

    float acc[10], acch[10];
#pragma unroll
    for (int p = 0; p < 10; ++p) { acc[p] = 0.f; acch[p] = 0.f; }

    for (int cb = 0; cb < C_DIM; cb += 8) {
        float vc[8], vch[8];
#pragma unroll
        for (int i = 0; i < 8; ++i) {
            vc[i] = Vsh[(cb + i) * 68 + ll];
            vch[i] = Vsh[(cb + i) * 68 + 63 - ll];
        }
#pragma unroll
        for (int p = 0; p < 10; ++p) {
#pragma unroll
            for (int q = 0; q < 2; ++q) {
                f4 w = *(const f4*)(wp + p * C_DIM + cb + q * 4);
                f4 wh = *(const f4*)(wph + p * C_DIM + cb + q * 4);
#pragma unroll
                for (int i = 0; i < 4; ++i) {
                    acc[p] = fmaf(w[i], vc[q * 4 + i], acc[p]);
                    acch[p] = fmaf(wh[i], vch[q * 4 + i], acch[p]);
                }
            }
        }
    }

    // ---- transpose via Psh, coalesced stores (g then gh) ----
#pragma unroll
    for (int gg = 0; gg < 2; ++gg) {
        __syncthreads();
#pragma unroll
        for (int p = 0; p < 10; ++p) Psh[P0 + p][ll] = gg ? acch[p] : acc[p];
        __syncthreads();
        int lb = gg ? l0h : l0;
        int bgx = gg ? bgh : bg;
        int q = tid & 3, lx = tid >> 2;
        f4 bv = { Psh[6 + q * 4 + 0][lx], Psh[6 + q * 4 + 1][lx],
                  Psh[6 + q * 4 + 2][lx], Psh[6 + q * 4 + 3][lx] };
        *(f4*)(Bsw + ((size_t)bgx * L_LEN + lb + lx) * N_DIM + q * 4) = bv;
        f4 cv = { Psh[22 + q * 4 + 0][lx], Psh[22 + q * 4 + 1][lx],
                  Psh[22 + q * 4 + 2][lx], Psh[22 + q * 4 + 3][lx] };
        *(f4*)(Csw + ((size_t)bgx * L_LEN + lb + lx) * N_DIM + q * 4) = cv;
        for (int e = tid; e < 64 * R_DIM; e += 256) {
            int lx2 = e / 6, r = e - (e / 6) * 6;
            dtsT[((size_t)bgx * L_LEN + lb + lx2) * R_DIM + r] = Psh[r][lx2];
        }
    }
}

// ---------------- K2: chunk-parallel scan, delta recomputed on the fly ----------------
__device__ __forceinline__ float softplus_f(float x)
{
    float sp = __logf(1.f + __expf(x));
    return (x > 60.f) ? x : sp;
}

// Pass A: per chunk with h0=0, compute h_end[16] and prodE[16]=exp2(a2*S).
__global__ __launch_bounds__(192) void k2_scanA(
    const float* __restrict__ dtsT, const float* __restrict__ Bsw,
    const float* __restrict__ u6T, const float* __restrict__ A_logs,
    const float* __restrict__ dtw, const float* __restrict__ dtb,
    float* __restrict__ hend, float* __restrict__ prodE)
{
    __shared__ f4 Bsh[256];     // 64 l x 16 n
    __shared__ float Dsh[384];  // 64 l x 6
    int blk = blockIdx.x;
    int chgrp = blk & 31;
    int bg = blk >> 5;
    int g = bg % G_DIM;
    int b = bg / G_DIM;
    int tid = (int)threadIdx.x;

    const f4* Bg = (const f4*)(Bsw + ((size_t)bg * L_LEN + chgrp * 64) * N_DIM);
    for (int i = tid; i < 256; i += 192) Bsh[i] = Bg[i];
    const float* Dg = dtsT + ((size_t)bg * L_LEN + chgrp * 64) * R_DIM;
    for (int i = tid; i < 384; i += 192) Dsh[i] = Dg[i];
    __syncthreads();

    int chl = tid / 96;
    int c = tid % 96;
    int ch = chgrp * 2 + chl;
    int bgc = bg * C_DIM + c;
    const bool rev = (g >= 6);
    int gu = rev ? (g - 6) : g;

    float a2[N_DIM];
    {
        const f4* Ap = (const f4*)(A_logs + ((size_t)g * C_DIM + c) * N_DIM);
        f4 Av[4] = { Ap[0], Ap[1], Ap[2], Ap[3] };
#pragma unroll
        for (int n = 0; n < N_DIM; ++n)
            a2[n] = -__expf(Av[n >> 2][n & 3]) * 1.44269504f;
    }
    float wdr[R_DIM];
    {
        const float* wdp = dtw + ((size_t)g * C_DIM + c) * R_DIM;
#pragma unroll
        for (int r = 0; r < R_DIM; ++r) wdr[r] = wdp[r];
    }
    float bias = dtb[g * C_DIM + c];

    const int LOFF = ch * CLEN;
    const float* up;
    int ustep;
    if (rev) { up = u6T + ((size_t)(b * 6 + gu) * L_LEN + (2047 - LOFF)) * C_DIM + c; ustep = -C_DIM; }
    else     { up = u6T + ((size_t)(b * 6 + gu) * L_LEN + LOFF) * C_DIM + c; ustep = C_DIM; }

    float h[N_DIM];
#pragma unroll
    for (int n = 0; n < N_DIM; ++n) h[n] = 0.f;
    float S = 0.f;

    float ubuf[4];
#pragma unroll
    for (int j = 0; j < 4; ++j) ubuf[j] = up[j * ustep];

    for (int jj = 0; jj < CLEN; jj += 4) {
        int nx = (jj + 4 < CLEN) ? jj + 4 : jj;
        float un[4];
#pragma unroll
        for (int j = 0; j < 4; ++j) un[j] = up[(nx + j) * ustep];
#pragma unroll
        for (int j = 0; j < 4; ++j) {
            int li = chl * CLEN + jj + j;
            float dt_ = bias;
#pragma unroll
            for (int r = 0; r < R_DIM; ++r) dt_ = fmaf(Dsh[li * R_DIM + r], wdr[r], dt_);
            float d = softplus_f(dt_);
            S += d;
            float du = d * ubuf[j];
            const f4* Bl = Bsh + (size_t)li * 4;
            f4 Bv[4] = { Bl[0], Bl[1], Bl[2], Bl[3] };
#pragma unroll
            for (int n = 0; n < N_DIM; ++n) {
                float e = fexp2(d * a2[n]);
                h[n] = fmaf(h[n], e, du * Bv[n >> 2][n & 3]);
            }
        }
#pragma unroll
        for (int j = 0; j < 4; ++j) ubuf[j] = un[j];
    }
    float* hp = hend + ((size_t)bgc * NCHUNK + ch) * N_DIM;
    float* pp = prodE + ((size_t)bgc * NCHUNK + ch) * N_DIM;
#pragma unroll
    for (int q = 0; q < 4; ++q) {
        f4 hv = { h[q * 4], h[q * 4 + 1], h[q * 4 + 2], h[q * 4 + 3] };
        f4 pv = { fexp2(a2[q * 4] * S), fexp2(a2[q * 4 + 1] * S),
                  fexp2(a2[q * 4 + 2] * S), fexp2(a2[q * 4 + 3] * S) };
        *(f4*)(hp + q * 4) = hv;
        *(f4*)(pp + q * 4) = pv;
    }
}

// Pass B: compose chunk propagators. Overwrites prodE with hstart (in place).
__global__ __launch_bounds__(256) void k2_fix(
    const float* __restrict__ hend, float* prodE_hstart)
{
    int t = blockIdx.x * 256 + (int)threadIdx.x; // 73728
    int n = t & 15;
    int bgc = t >> 4;
    float h = 0.f;
    for (int ch = 0; ch < NCHUNK; ++ch) {
        size_t idx = ((size_t)bgc * NCHUNK + ch) * N_DIM + n;
        float Pv = prodE_hstart[idx];
        float he = hend[idx];
        prodE_hstart[idx] = h;
        h = fmaf(h, Pv, he);
    }
}

// Pass C: exact recurrence from hstart, writes yT [bg][l][c] (+Ds*u folded).
__global__ __launch_bounds__(192) void k2_scanC(
    const float* __restrict__ dtsT, const float* __restrict__ Bsw,
    const float* __restrict__ Csw, const float* __restrict__ u6T,
    const float* __restrict__ A_logs, const float* __restrict__ Ds,
    const float* __restrict__ dtw, const float* __restrict__ dtb,
    const float* __restrict__ hstart, float* __restrict__ yssT)
{
    __shared__ f4 Bsh[256];
    __shared__ f4 Csh[256];
    __shared__ float Dsh[384];
    int blk = blockIdx.x;
    int chgrp = blk & 31;
    int bg = blk >> 5;
    int g = bg % G_DIM;
    int b = bg / G_DIM;
    int tid = (int)threadIdx.x;

    const f4* Bg = (const f4*)(Bsw + ((size_t)bg * L_LEN + chgrp * 64) * N_DIM);
    const f4* Cg = (const f4*)(Csw + ((size_t)bg * L_LEN + chgrp * 64) * N_DIM);
    for (int i = tid; i < 256; i += 192) { Bsh[i] = Bg[i]; Csh[i] = Cg[i]; }
    const float* Dg = dtsT + ((size_t)bg * L_LEN + chgrp * 64) * R_DIM;
    for (int i = tid; i < 384; i += 192) Dsh[i] = Dg[i];
    __syncthreads();

    int chl = tid / 96;
    int c = tid % 96;
    int ch = chgrp * 2 + chl;
    int bgc = bg * C_DIM + c;
    const bool rev = (g >= 6);
    int gu = rev ? (g - 6) : g;

    float a2[N_DIM];
    {
        const f4* Ap = (const f4*)(A_logs + ((size_t)g * C_DIM + c) * N_DIM);
        f4 Av[4] = { Ap[0], Ap[1], Ap[2], Ap[3] };
#pragma unroll
        for (int n = 0; n < N_DIM; ++n)
            a2[n] = -__expf(Av[n >> 2][n & 3]) * 1.44269504f;
    }
    float wdr[R_DIM];
    {
        const float* wdp = dtw + ((size_t)g * C_DIM + c) * R_DIM;
#pragma unroll
        for (int r = 0; r < R_DIM; ++r) wdr[r] = wdp[r];
    }
    float bias = dtb[g * C_DIM + c];
    float dsc = Ds[g * C_DIM + c];

    const int LOFF = ch * CLEN;
    const float* up;
    int ustep;
    if (rev) { up = u6T + ((size_t)(b * 6 + gu) * L_LEN + (2047 - LOFF)) * C_DIM + c; ustep = -C_DIM; }
    else     { up = u6T + ((size_t)(b * 6 + gu) * L_LEN + LOFF) * C_DIM + c; ustep = C_DIM; }
    float* yp = yssT + ((size_t)bg * L_LEN + LOFF) * C_DIM + c;

    float h[N_DIM];
    {
        const f4* Hp = (const f4*)(hstart + ((size_t)bgc * NCHUNK + ch) * N_DIM);
        f4 Hv[4] = { Hp[0], Hp[1], Hp[2], Hp[3] };
#pragma unroll
        for (int n = 0; n < N_DIM; ++n) h[n] = Hv[n >> 2][n & 3];
    }

    float ubuf[4];
#pragma unroll
    for (int j = 0; j < 4; ++j) ubuf[j] = up[j * ustep];

    for (int jj = 0; jj < CLEN; jj += 4) {
        int nx = (jj + 4 < CLEN) ? jj + 4 : jj;
        float un[4];
#pragma unroll
        for (int j = 0; j < 4; ++j) un[j] = up[(nx + j) * ustep];
#pragma unroll
        for (int j = 0; j < 4; ++j) {
            int li = chl * CLEN + jj + j;
            float dt_ = bias;
#pragma unroll
            for (int r = 0; r < R_DIM; ++r) dt_ = fmaf(Dsh[li * R_DIM + r], wdr[r], dt_);
            float d = softplus_f(dt_);
            float uu = ubuf[j];
            float du = d * uu;
            const f4* Bl = Bsh + (size_t)li * 4;
            const f4* Cl = Csh + (size_t)li * 4;
            f4 Bv[4] = { Bl[0], Bl[1], Bl[2], Bl[3] };
            f4 Cv[4] = { Cl[0], Cl[1], Cl[2], Cl[3] };
            // 4 partial y accumulators to shorten the dependent fma chain
            float y0 = dsc * uu, y1 = 0.f, y2 = 0.f, y3 = 0.f;
#pragma unroll
            for (int q = 0; q < 4; ++q) {
                float e0 = fexp2(d * a2[q * 4 + 0]);
                float e1 = fexp2(d * a2[q * 4 + 1]);
                float e2 = fexp2(d * a2[q * 4 + 2]);
                float e3 = fexp2(d * a2[q * 4 + 3]);
                h[q * 4 + 0] = fmaf(h[q * 4 + 0], e0, du * Bv[q][0]);
                h[q * 4 + 1] = fmaf(h[q * 4 + 1], e1, du * Bv[q][1]);
                h[q * 4 + 2] = fmaf(h[q * 4 + 2], e2, du * Bv[q][2]);
                h[q * 4 + 3] = fmaf(h[q * 4 + 3], e3, du * Bv[q][3]);
                y0 = fmaf(h[q * 4 + 0], Cv[q][0], y0);
                y1 = fmaf(h[q * 4 + 1], Cv[q][1], y1);
                y2 = fmaf(h[q * 4 + 2], Cv[q][2], y2);
                y3 = fmaf(h[q * 4 + 3], Cv[q][3], y3);
            }
            yp[(jj + j) * C_DIM] = (y0 + y1) + (y2 + y3);
        }
#pragma unroll
        for (int j = 0; j < 4; ++j) ubuf[j] = un[j];
    }
}

// ---------------- K3: fold (un-scan) + LayerNorm, fused ([l][c] input) ----------------
__global__ __launch_bounds__(256) void k3_out(
    const float* __restrict__ yssT, const float* __restrict__ nw,
    const float* __restrict__ nb, float* __restrict__ out)
{
    __shared__ float tA[32][97];
    __shared__ float tB[32][97];
    __shared__ float ps[4][8][32];
    __shared__ float stat[4][32];

    int blk = blockIdx.x;
    int h = blk & 31;
    int bs = blk >> 5;
    int so = bs & 1;
    int b = bs >> 1;
    int tid = (int)threadIdx.x;

    auto Y = [&](int g) { return yssT + (size_t)(b * 12 + g) * L_LEN * C_DIM; };
    const float* Y0 = Y(so);
    const float* Y0r = Y(6 + so);
    const float* Y1 = Y(3 + so);
    const float* Y1r = Y(9 + so);

#pragma unroll 2
    for (int it = 0; it < 24; ++it) {
        int idx = tid + it * 256;
        int c = idx % 96, rest = idx / 96;
        int w = rest >> 1, par = rest & 1;
        int a0 = h * 64 + rest;
        int a1 = w * 64 + 2 * h + par;
        float v = Y0[(size_t)a0 * C_DIM + c] + Y0r[(size_t)(2047 - a0) * C_DIM + c]
                + Y1[(size_t)a1 * C_DIM + c] + Y1r[(size_t)(2047 - a1) * C_DIM + c];
        if (par) tA[w][c] = v; else tB[w][c] = v;
    }
    __syncthreads();

    int w = tid & 31, cg = tid >> 5;
    float sA = 0, qA = 0, sB = 0, qB = 0;
#pragma unroll
    for (int j = 0; j < 12; ++j) {
        float yv = tA[w][cg * 12 + j], dv = tB[w][cg * 12 + j];
        sA += yv; qA += yv * yv; sB += dv; qB += dv * dv;
    }
    ps[0][cg][w] = sA; ps[1][cg][w] = qA; ps[2][cg][w] = sB; ps[3][cg][w] = qB;
    __syncthreads();
    if (tid < 32) {
        int ww = tid;
        float t0 = 0, t1 = 0, t2 = 0, t3 = 0;
#pragma unroll
        for (int q = 0; q < 8; ++q) {
            t0 += ps[0][q][ww]; t1 += ps[1][q][ww];
            t2 += ps[2][q][ww]; t3 += ps[3][q][ww];
        }
        float muA = t0 * (1.f / 96.f), eqA = t1 * (1.f / 96.f);
        float muB = t2 * (1.f / 96.f), eqB = t3 * (1.f / 96.f);
        stat[0][ww] = muA; stat[1][ww] = rsqrtf(eqA - muA * muA + 1e-5f);
        stat[2][ww] = muB; stat[3][ww] = rsqrtf(eqB - muB * muB + 1e-5f);
    }
    __syncthreads();
    size_t obase = (size_t)blk * 3072;
    for (int e = tid; e < 3072; e += 256) {
        int ww = e / 96, c = e % 96;
        float wc = nw[c], bc = nb[c];
        out[obase + e] = (tA[ww][c] - stat[0][ww]) * stat[1][ww] * wc + bc;
        out[2 * 786432 + obase + e] = (tB[ww][c] - stat[2][ww]) * stat[3][ww] * wc + bc;
    }
    __syncthreads();

    const float* Y2 = Y(2);
    const float* Y2r = Y(8);
    const float* Y3 = Y(5);
    const float* Y3r = Y(11);
#pragma unroll 2
    for (int it = 0; it < 12; ++it) {
        int idx = tid + it * 256;
        int c = idx % 96, w2 = idx / 96;
        int a0 = h * 64 + 2 * w2 + so;
        int a1 = w2 * 64 + 2 * h + so;
        float v = Y2[(size_t)a0 * C_DIM + c] + Y2r[(size_t)(2047 - a0) * C_DIM + c]
                + Y3[(size_t)a1 * C_DIM + c] + Y3r[(size_t)(2047 - a1) * C_DIM + c];
        tA[w2][c] = v;
    }
    __syncthreads();
    float sC = 0, qC = 0;
#pragma unroll
    for (int j = 0; j < 12; ++j) {
        float v = tA[w][cg * 12 + j];
        sC += v; qC += v * v;
    }
    ps[0][cg][w] = sC; ps[1][cg][w] = qC;
    __syncthreads();
    if (tid < 32) {
        int ww = tid;
        float t0 = 0, t1 = 0;
#pragma unroll
        for (int q = 0; q < 8; ++q) { t0 += ps[0][q][ww]; t1 += ps[1][q][ww]; }
        float mu = t0 * (1.f / 96.f), eq = t1 * (1.f / 96.f);
        stat[0][ww] = mu; stat[1][ww] = rsqrtf(eq - mu * mu + 1e-5f);
    }
    __syncthreads();
    for (int e = tid; e < 3072; e += 256) {
        int ww = e / 96, c = e % 96;
        out[786432 + obase + e] = (tA[ww][c] - stat[0][ww]) * stat[1][ww] * nw[c] + nb[c];
    }
}

extern "C" void kernel_launch(void* const* d_in, const int* in_sizes, int n_in,
                              void* d_out, int out_size, void* d_ws, size_t ws_size,
                              hipStream_t stream)
{
    const float* x = (const float*)d_in[0];
    const float* xpw = (const float*)d_in[1];
    const float* dtw = (const float*)d_in[2];
    const float* dtb = (const float*)d_in[3];
    const float* A_logs = (const float*)d_in[4];
    const float* Ds = (const float*)d_in[5];
    const float* nw = (const float*)d_in[6];
    const float* nb = (const float*)d_in[7];
    float* out = (float*)d_out;

    float* ws = (float*)d_ws;
    float* dtsT = ws;                  // SZ_DTS
    float* Bsw = dtsT + SZ_DTS;        // SZ_BC
    float* Csw = Bsw + SZ_BC;          // SZ_BC
    float* u6T = Csw + SZ_BC;          // SZ_U6
    float* yssT = u6T + SZ_U6;         // SZ_Y
    float* hend = yssT + SZ_Y;         // SZ_H
    float* prodE = hend + SZ_H;        // SZ_H (then reused as hstart)
    float* xT = prodE + SZ_H;          // SZ_X
    float* wpad = xT + SZ_X;           // SZ_WPAD

    k0_xT<<<dim3(768), dim3(256), 0, stream>>>(x, xT);
    k0b_padw<<<dim3(180), dim3(256), 0, stream>>>(xpw, wpad);
    k1_proj<<<dim3(24 * 32), dim3(256), 0, stream>>>(x, xT, wpad, dtsT, Bsw, Csw, u6T);
    k2_scanA<<<dim3(48 * 32), dim3(192), 0, stream>>>(dtsT, Bsw, u6T, A_logs, dtw, dtb, hend, prodE);
    k2_fix<<<dim3(288), dim3(256), 0, stream>>>(hend, prodE);
    k2_scanC<<<dim3(48 * 32), dim3(192), 0, stream>>>(dtsT, Bsw, Csw, u6T, A_logs, Ds, dtw, dtb, prodE, yssT);
    k3_out<<<dim3(256), dim3(256), 0, stream>>>(yssT, nw, nb, out);
}